// Round 13
// baseline (100.782 us; speedup 1.0000x reference)
//
#include <hip/hip_runtime.h>

typedef __attribute__((ext_vector_type(8))) short bf16x8;
typedef __attribute__((ext_vector_type(4))) float f32x4;

#define NB 1024
#define NC 64
#define NT 512
#define ND 32

__device__ __forceinline__ unsigned short f2bf(float f) {
  unsigned u = __float_as_uint(f);
  u += 0x7FFFu + ((u >> 16) & 1u);   // round-to-nearest-even (finite values)
  return (unsigned short)(u >> 16);
}

// ---- prep: rearrange weights into MFMA B-fragment order (bf16) ----
// ws layout (ushort elements):
//   [0,16384)      Win  frags [ks(16)][nt(2)][lane(64)][j(8)]   B[k][n], k=32ks+8(l>>4)+j, n=16nt+(l&15)
//   [16384,32768)  Wout frags [nt(32)][lane(64)][j(8)]
//   [32768,33792)  Wq   frags [nt(2)][lane(64)][j(8)]
//   [33792,34816)  Wk   frags
//   [34816,35840)  Wv   frags
__global__ void prep_weights(const float* __restrict__ Win, const float* __restrict__ Wq,
                             const float* __restrict__ Wk, const float* __restrict__ Wv,
                             const float* __restrict__ Wout, unsigned short* __restrict__ ws) {
  int idx = blockIdx.x * 256 + threadIdx.x;
  if (idx >= 35840) return;
  float v;
  if (idx < 16384) {
    int j = idx & 7, lane = (idx >> 3) & 63, nt = (idx >> 9) & 1, ks = idx >> 10;
    int t = 32 * ks + 8 * (lane >> 4) + j;
    int d = 16 * nt + (lane & 15);
    v = Win[t * ND + d];
  } else if (idx < 32768) {
    int p = idx - 16384;
    int j = p & 7, lane = (p >> 3) & 63, nt = (p >> 9) & 31;
    int k = 8 * (lane >> 4) + j;
    int n = 16 * nt + (lane & 15);
    v = Wout[k * NT + n];
  } else {
    int p = idx - 32768;
    const float* W = (p < 1024) ? Wq : ((p < 2048) ? Wk : Wv);
    int q = p & 1023;
    int j = q & 7, lane = (q >> 3) & 63, nt = (q >> 9) & 1;
    int t = 8 * (lane >> 4) + j;
    int d = 16 * nt + (lane & 15);
    v = W[t * ND + d];
  }
  ws[idx] = f2bf(v);
}

// ======================= Kernel A: x -> h -> q/k/v -> attention -> o stash ====
// Pure read-stream kernel: 134 MB x in (HBM), 4 MB o out. o-frag (16 B/thread)
// goes to the LAST 1024 FLOATS of this block's 32768-float d_out region
// (rows 62-63): float offset 31744 .. 32768. Kernel B reads it before
// overwriting. (R12 bug: offset was 63488 floats = out of region -> fault.)
__global__ __launch_bounds__(256, 4)
void mha_a(const float* __restrict__ x, const float* __restrict__ b_in,
           const unsigned short* __restrict__ wsb, float* __restrict__ ostash) {
  __shared__ __align__(16) unsigned short lds_h[4][64][8];
  __shared__ __align__(16) float lds_q[64][36];
  __shared__ __align__(16) float lds_k[64][36];
  __shared__ __align__(16) float lds_v[64][36];

  const int tid = threadIdx.x;
  const int w  = tid >> 6;   // wave id
  const int l  = tid & 63;   // lane
  const int g  = l >> 4;     // quarter-wave group
  const int lo = l & 15;
  const int b  = blockIdx.x;
  const float* __restrict__ xb = x + (size_t)b * (NC * NT);

  // ---------------- P1: h = x @ W_in + b_in  (A-frags loaded from global) -------
  const int srow = 16 * w + lo;
  const float* __restrict__ xr = xb + srow * NT + 8 * g;
  const bf16x8* __restrict__ wsWin = (const bf16x8*)wsb;

  f32x4 zero4 = (f32x4){0.f, 0.f, 0.f, 0.f};
  f32x4 acc1[2];
  acc1[0] = zero4;
  acc1[1] = zero4;
  f32x4 ra = *(const f32x4*)(xr);
  f32x4 rb = *(const f32x4*)(xr + 4);
  bf16x8 bp0 = wsWin[l];
  bf16x8 bp1 = wsWin[64 + l];

#pragma unroll
  for (int ks = 0; ks < 16; ++ks) {
    bf16x8 af;
    af[0] = (short)f2bf(ra[0]); af[1] = (short)f2bf(ra[1]);
    af[2] = (short)f2bf(ra[2]); af[3] = (short)f2bf(ra[3]);
    af[4] = (short)f2bf(rb[0]); af[5] = (short)f2bf(rb[1]);
    af[6] = (short)f2bf(rb[2]); af[7] = (short)f2bf(rb[3]);
    int nk = (ks < 15) ? (ks + 1) : 15;   // prefetch next chunk (clamped)
    f32x4 ra2 = *(const f32x4*)(xr + 32 * nk);
    f32x4 rb2 = *(const f32x4*)(xr + 32 * nk + 4);
    bf16x8 bn0 = wsWin[(2 * nk) * 64 + l];
    bf16x8 bn1 = wsWin[(2 * nk + 1) * 64 + l];
    acc1[0] = __builtin_amdgcn_mfma_f32_16x16x32_bf16(af, bp0, acc1[0], 0, 0, 0);
    acc1[1] = __builtin_amdgcn_mfma_f32_16x16x32_bf16(af, bp1, acc1[1], 0, 0, 0);
    ra = ra2; rb = rb2; bp0 = bn0; bp1 = bn1;
  }

  float binv0 = b_in[lo];
  float binv1 = b_in[16 + lo];
  // D-frag: row = 16w + 4g + r, col = 16nt + lo  -> h into frag-direct LDS (bf16)
#pragma unroll
  for (int nt = 0; nt < 2; ++nt) {
#pragma unroll
    for (int r = 0; r < 4; ++r) {
      float hv = acc1[nt][r] + (nt ? binv1 : binv0);
      int cc = 2 * nt + (lo >> 3);
      int slotlane = (4 * g + r) | (cc << 4);
      lds_h[w][slotlane][lo & 7] = f2bf(hv);
    }
  }
  // NO barrier: lds_h[w] written and read by the same wave (lgkmcnt orders it)

  // ---------------- P2: q/k/v = h @ Wq/Wk/Wv  (6 MFMAs per wave) ----------------
  const bf16x8* __restrict__ wsWq = (const bf16x8*)(wsb + 32768);
  const bf16x8* __restrict__ wsWk = (const bf16x8*)(wsb + 33792);
  const bf16x8* __restrict__ wsWv = (const bf16x8*)(wsb + 34816);
  bf16x8 ah = *(const bf16x8*)&lds_h[w][l][0];
  f32x4 qacc[2], kacc[2], vacc[2];
#pragma unroll
  for (int nt = 0; nt < 2; ++nt) {
    qacc[nt] = __builtin_amdgcn_mfma_f32_16x16x32_bf16(ah, wsWq[nt * 64 + l], zero4, 0, 0, 0);
    kacc[nt] = __builtin_amdgcn_mfma_f32_16x16x32_bf16(ah, wsWk[nt * 64 + l], zero4, 0, 0, 0);
    vacc[nt] = __builtin_amdgcn_mfma_f32_16x16x32_bf16(ah, wsWv[nt * 64 + l], zero4, 0, 0, 0);
  }
#pragma unroll
  for (int nt = 0; nt < 2; ++nt) {
#pragma unroll
    for (int r = 0; r < 4; ++r) {
      int row = 16 * w + 4 * g + r;
      int col = 16 * nt + lo;
      lds_q[row][col] = qacc[nt][r];
      lds_k[row][col] = kacc[nt][r];
      lds_v[row][col] = vacc[nt][r];
    }
  }
  __syncthreads();   // the only barrier: k/v read cross-wave in P3

  // ---------------- P3: attention, online no-max softmax ------------------------
  // thread (w,l) owns channel c = 16w+lo, head hd = g  ->  o[c][8g+j] IS the
  // P4 A-frag element for wave w (lane l: row lo, k = 8g+j). Store to stash.
  {
    const int c = 16 * w + lo;
    const f32x4 qv0 = *(const f32x4*)&lds_q[c][8 * g];
    const f32x4 qv1 = *(const f32x4*)&lds_q[c][8 * g + 4];
    float sum = 0.f;
    float ov[8] = {0.f, 0.f, 0.f, 0.f, 0.f, 0.f, 0.f, 0.f};
#pragma unroll 4
    for (int kk = 0; kk < 64; ++kk) {
      f32x4 k0 = *(const f32x4*)&lds_k[kk][8 * g];
      f32x4 k1 = *(const f32x4*)&lds_k[kk][8 * g + 4];
      float s = qv0[0] * k0[0] + qv0[1] * k0[1] + qv0[2] * k0[2] + qv0[3] * k0[3]
              + qv1[0] * k1[0] + qv1[1] * k1[1] + qv1[2] * k1[2] + qv1[3] * k1[3];
      float p = exp2f(s * (1.4426950408889634f * 0.35355339059327373f));
      sum += p;
      f32x4 v0 = *(const f32x4*)&lds_v[kk][8 * g];
      f32x4 v1 = *(const f32x4*)&lds_v[kk][8 * g + 4];
      ov[0] += p * v0[0]; ov[1] += p * v0[1]; ov[2] += p * v0[2]; ov[3] += p * v0[3];
      ov[4] += p * v1[0]; ov[5] += p * v1[1]; ov[6] += p * v1[2]; ov[7] += p * v1[3];
    }
    float inv = 1.0f / sum;
    bf16x8 a4;
#pragma unroll
    for (int d = 0; d < 8; ++d) a4[d] = (short)f2bf(ov[d] * inv);
    // stash at float offset 31744 of THIS block's region: [31744, 32768) floats
    bf16x8* __restrict__ stash =
        (bf16x8*)(ostash + (size_t)b * (NC * NT) + 31744);
    stash[w * 64 + l] = a4;
  }
}

// ======================= Kernel B: y = o @ W_out + b_out + x, LayerNorm =======
// R6's proven 2-pass P4 (48 VGPR, no spill), zero data LDS. Streams:
// write 134 MB y (HBM) + read 2x134 MB x (L3-resident) + o stash (L3).
__global__ __launch_bounds__(256, 4)
void mha_b(const float* __restrict__ x, const float* __restrict__ b_out,
           const float* __restrict__ gamma, const float* __restrict__ beta,
           const unsigned short* __restrict__ wsb, float* __restrict__ out) {
  const int tid = threadIdx.x;
  const int w  = tid >> 6;
  const int l  = tid & 63;
  const int g  = l >> 4;
  const int lo = l & 15;
  const int b  = blockIdx.x;
  const float* __restrict__ xb = x + (size_t)b * (NC * NT);
  float* __restrict__ ob = out + (size_t)b * (NC * NT);

  // read this wave's o frag stashed by kernel A (float offset 31744 = rows 62-63)
  const bf16x8* __restrict__ stash = (const bf16x8*)(ob + 31744);
  const bf16x8 a4 = stash[w * 64 + l];
  __syncthreads();   // all stash loads drained before any store below

  f32x4 zero4 = (f32x4){0.f, 0.f, 0.f, 0.f};
  const bf16x8* __restrict__ wsWout = (const bf16x8*)(wsb + 16384);
  const int row0 = 16 * w + 4 * g;
  const float* __restrict__ xrow = xb + row0 * NT + lo;

  float s1[4] = {0.f, 0.f, 0.f, 0.f};
  float s2[4] = {0.f, 0.f, 0.f, 0.f};

  // ---- pass 1: statistics only (one MFMA acc live) ----
#pragma unroll 4
  for (int nt = 0; nt < 32; ++nt) {
    bf16x8 bfr = wsWout[nt * 64 + l];
    f32x4 acc = __builtin_amdgcn_mfma_f32_16x16x32_bf16(a4, bfr, zero4, 0, 0, 0);
    int col = 16 * nt;
    float bo = b_out[col + lo];
#pragma unroll
    for (int r = 0; r < 4; ++r) {
      float y = acc[r] + bo + xrow[r * NT + col];
      s1[r] += y;
      s2[r] += y * y;
    }
  }
  // LN reduce: each row's 512 cols live in the 16 lanes sharing g
#pragma unroll
  for (int off = 1; off <= 8; off <<= 1) {
#pragma unroll
    for (int r = 0; r < 4; ++r) {
      s1[r] += __shfl_xor(s1[r], off, 64);
      s2[r] += __shfl_xor(s2[r], off, 64);
    }
  }
  float mu[4], rs[4];
#pragma unroll
  for (int r = 0; r < 4; ++r) {
    mu[r] = s1[r] * (1.0f / 512.0f);
    float var = s2[r] * (1.0f / 512.0f) - mu[r] * mu[r];
    rs[r] = rsqrtf(var + 1e-5f);
  }

  // ---- pass 2: recompute identical MFMAs, normalize, store ----
  float* __restrict__ orow = ob + row0 * NT + lo;
#pragma unroll 4
  for (int nt = 0; nt < 32; ++nt) {
    bf16x8 bfr = wsWout[nt * 64 + l];
    f32x4 acc = __builtin_amdgcn_mfma_f32_16x16x32_bf16(a4, bfr, zero4, 0, 0, 0);
    int col = 16 * nt;
    float bo = b_out[col + lo];
    float gm = gamma[col + lo];
    float bt = beta[col + lo];
#pragma unroll
    for (int r = 0; r < 4; ++r) {
      float y = acc[r] + bo + xrow[r * NT + col];
      orow[r * NT + col] = (y - mu[r]) * rs[r] * gm + bt;
    }
  }
}

extern "C" void kernel_launch(void* const* d_in, const int* in_sizes, int n_in,
                              void* d_out, int out_size, void* d_ws, size_t ws_size,
                              hipStream_t stream) {
  const float* x     = (const float*)d_in[0];
  const float* W_in  = (const float*)d_in[1];
  const float* b_in  = (const float*)d_in[2];
  const float* W_q   = (const float*)d_in[3];
  const float* W_k   = (const float*)d_in[4];
  const float* W_v   = (const float*)d_in[5];
  const float* W_out = (const float*)d_in[6];
  const float* b_out = (const float*)d_in[7];
  const float* gamma = (const float*)d_in[8];
  const float* beta  = (const float*)d_in[9];
  unsigned short* ws = (unsigned short*)d_ws;

  prep_weights<<<140, 256, 0, stream>>>(W_in, W_q, W_k, W_v, W_out, ws);
  mha_a<<<NB, 256, 0, stream>>>(x, b_in, ws, (float*)d_out);
  mha_b<<<NB, 256, 0, stream>>>(x, b_out, gamma, beta, ws, (float*)d_out);
}